// Round 1
// baseline (1834.681 us; speedup 1.0000x reference)
//
#include <hip/hip_runtime.h>
#include <math.h>

#define NN 10000
#define NE 160000
#define E2 (NE + NN)
#define NG 20

// ---------- helpers ----------
__device__ inline unsigned fenc(float f){ unsigned u=__float_as_uint(f); return (u&0x80000000u)?~u:(u|0x80000000u); }
__device__ inline float fdec(unsigned u){ return __uint_as_float((u&0x80000000u)?(u&0x7FFFFFFFu):~u); }

// ---------- graph boundary (batch is sorted) ----------
__global__ void k_gptr(const int* __restrict__ batch, int* __restrict__ gptr){
  int g = threadIdx.x;
  if (g > NG) return;
  int lo = 0, hi = NN;
  while (lo < hi){ int mid = (lo+hi)>>1; if (batch[mid] < g) lo = mid+1; else hi = mid; }
  gptr[g] = lo;
}

// ---------- CSR build (by dst, self-loops appended) ----------
__global__ void k_count(const int* __restrict__ ei, int* __restrict__ cnt){
  int e = blockIdx.x*256 + threadIdx.x;
  if (e >= E2) return;
  int d = (e < NE) ? ei[NE + e] : (e - NE);
  atomicAdd(&cnt[d], 1);
}

__global__ void k_scan(const int* __restrict__ cnt, int* __restrict__ ptr){
  // single block, 256 threads, n = NN
  __shared__ int tpre[256];
  __shared__ int tsum[256];
  int tid = threadIdx.x;
  const int per = (NN + 255)/256;
  int base = tid*per;
  int s = 0;
  for (int i=0;i<per;i++){ int idx=base+i; if (idx<NN) s += cnt[idx]; }
  tsum[tid] = s;
  __syncthreads();
  if (tid == 0){
    int run = 0;
    for (int i=0;i<256;i++){ tpre[i]=run; run += tsum[i]; }
    ptr[NN] = run;
  }
  __syncthreads();
  int run = tpre[tid];
  for (int i=0;i<per;i++){ int idx=base+i; if (idx<NN){ ptr[idx]=run; run += cnt[idx]; } }
}

__global__ void k_copy(const int* __restrict__ src, int* __restrict__ dst){
  int i = blockIdx.x*256 + threadIdx.x;
  if (i < NN) dst[i] = src[i];
}

__global__ void k_scatter(const int* __restrict__ ei, int* __restrict__ fill, int* __restrict__ csrc){
  int e = blockIdx.x*256 + threadIdx.x;
  if (e >= E2) return;
  int s, d;
  if (e < NE){ s = ei[e]; d = ei[NE + e]; } else { s = d = e - NE; }
  int pos = atomicAdd(&fill[d], 1);
  csrc[pos] = s;
}

// ---------- fp32 tiled GEMM: C[M,N] = A[M,K] x B[K,N] ----------
#define BM 64
#define BN 64
#define BK 16
__global__ __launch_bounds__(256) void k_gemm(const float* __restrict__ A, const float* __restrict__ B,
                       float* __restrict__ C, int M, int K, int N){
  __shared__ float sA[BK][BM];
  __shared__ float sB[BK][BN];
  int tx = threadIdx.x & 15, ty = threadIdx.x >> 4;
  int row0 = blockIdx.x * BM, col0 = blockIdx.y * BN;
  float acc[4][4] = {};
  for (int k0 = 0; k0 < K; k0 += BK){
    for (int i = threadIdx.x; i < BM*BK; i += 256){
      int r = i >> 4, c = i & 15;       // BK = 16
      int gr = row0 + r, gc = k0 + c;
      sA[c][r] = (gr < M && gc < K) ? A[(size_t)gr*K + gc] : 0.f;
    }
    for (int i = threadIdx.x; i < BK*BN; i += 256){
      int r = i >> 6, c = i & 63;       // BN = 64
      int gr = k0 + r, gc = col0 + c;
      sB[r][c] = (gr < K && gc < N) ? B[(size_t)gr*N + gc] : 0.f;
    }
    __syncthreads();
    #pragma unroll
    for (int kk = 0; kk < BK; ++kk){
      float a[4], b[4];
      #pragma unroll
      for (int i=0;i<4;i++) a[i] = sA[kk][ty*4+i];
      #pragma unroll
      for (int j=0;j<4;j++) b[j] = sB[kk][tx*4+j];
      #pragma unroll
      for (int i=0;i<4;i++)
        #pragma unroll
        for (int j=0;j<4;j++) acc[i][j] += a[i]*b[j];
    }
    __syncthreads();
  }
  #pragma unroll
  for (int i=0;i<4;i++){
    int gr = row0 + ty*4 + i; if (gr >= M) continue;
    #pragma unroll
    for (int j=0;j<4;j++){
      int gc = col0 + tx*4 + j;
      if (gc < N) C[(size_t)gr*N + gc] = acc[i][j];
    }
  }
}

// ---------- per-node per-head attention halves ----------
__global__ void k_attprep(const float* __restrict__ h, const float* __restrict__ atts, const float* __restrict__ attd,
                          float* __restrict__ a_s, float* __restrict__ a_d, int H, int C){
  int node = blockIdx.x, head = blockIdx.y;
  int lane = threadIdx.x;           // 64
  int F = H*C;
  const float* hp = h + (size_t)node*F + head*C;
  const float* sp = atts + head*C;
  const float* dp = attd + head*C;
  float ss = 0.f, sd = 0.f;
  for (int c = lane; c < C; c += 64){ float v = hp[c]; ss += v*sp[c]; sd += v*dp[c]; }
  #pragma unroll
  for (int o = 32; o; o >>= 1){ ss += __shfl_down(ss, o); sd += __shfl_down(sd, o); }
  if (lane == 0){ a_s[node*H + head] = ss; a_d[node*H + head] = sd; }
}

// ---------- fused edge-softmax + weighted gather (one block per dst node) ----------
#define CHUNK 128
__global__ __launch_bounds__(256) void k_gather(const float* __restrict__ h, const float* __restrict__ a_s, const float* __restrict__ a_d,
                         const int* __restrict__ ptr, const int* __restrict__ csrc,
                         const float* __restrict__ bias, float* __restrict__ out, int H, int C){
  int node = blockIdx.x;
  int F = H*C;
  int beg = ptr[node], deg = ptr[node+1] - beg;
  __shared__ unsigned smaxu[4];
  __shared__ float smax[4], ssum[4];
  __shared__ int ssrc[CHUNK];
  __shared__ float salpha[CHUNK*4];
  int tid = threadIdx.x;
  if (tid < H){ smaxu[tid] = fenc(-INFINITY); ssum[tid] = 0.f; }
  __syncthreads();
  // pass 1: per-head max of leaky_relu(e)
  for (int i = tid; i < deg*H; i += 256){
    int e = i / H, hh = i - e*H;
    int s = csrc[beg + e];
    float ev = a_s[s*H + hh] + a_d[node*H + hh];
    ev = ev > 0.f ? ev : 0.2f*ev;
    atomicMax(&smaxu[hh], fenc(ev));
  }
  __syncthreads();
  if (tid < H) smax[tid] = fdec(smaxu[tid]);
  __syncthreads();
  // pass 2: per-head denom
  for (int i = tid; i < deg*H; i += 256){
    int e = i / H, hh = i - e*H;
    int s = csrc[beg + e];
    float ev = a_s[s*H + hh] + a_d[node*H + hh];
    ev = ev > 0.f ? ev : 0.2f*ev;
    atomicAdd(&ssum[hh], __expf(ev - smax[hh]));
  }
  __syncthreads();
  // pass 3: chunked weighted gather
  float acc[4] = {0.f, 0.f, 0.f, 0.f};
  int hd[4];
  int nci = (F + 255) / 256;
  for (int ci = 0; ci < nci; ci++){ int c = tid + ci*256; hd[ci] = (c < F) ? c / C : 0; }
  for (int c0 = 0; c0 < deg; c0 += CHUNK){
    int cn = min(CHUNK, deg - c0);
    for (int i = tid; i < cn*H; i += 256){
      int e = i / H, hh = i - e*H;
      int s = csrc[beg + c0 + e];
      if (hh == 0) ssrc[e] = s;
      float ev = a_s[s*H + hh] + a_d[node*H + hh];
      ev = ev > 0.f ? ev : 0.2f*ev;
      salpha[e*H + hh] = __expf(ev - smax[hh]) / (ssum[hh] + 1e-16f);
    }
    __syncthreads();
    for (int e = 0; e < cn; e++){
      const float* hp = h + (size_t)ssrc[e]*F;
      float al0 = salpha[e*H + hd[0]];
      for (int ci = 0; ci < nci; ci++){
        int c = tid + ci*256;
        if (c < F) acc[ci] += hp[c] * ((ci == 0) ? al0 : salpha[e*H + hd[ci]]);
      }
    }
    __syncthreads();
  }
  for (int ci = 0; ci < nci; ci++){
    int c = tid + ci*256;
    if (c < F) out[(size_t)node*F + c] = acc[ci] + bias[c];
  }
}

// ---------- GraphNorm stats / coefs / apply+ELU ----------
#define NSPLIT 16
__global__ void k_gnstats(const float* __restrict__ x, const int* __restrict__ gptr,
                          float* __restrict__ gsum, float* __restrict__ gsq, int F){
  int g = blockIdx.x, cc = blockIdx.y, sp = blockIdx.z;
  int c = cc*256 + threadIdx.x;
  if (c >= F) return;
  int beg = gptr[g], end = gptr[g+1];
  int n = end - beg;
  int per = (n + NSPLIT - 1) / NSPLIT;
  int nb = beg + sp*per, ne = min(end, nb + per);
  if (ne <= nb) return;
  float s = 0.f, q = 0.f;
  for (int i = nb; i < ne; i++){ float v = x[(size_t)i*F + c]; s += v; q += v*v; }
  atomicAdd(&gsum[g*F + c], s);
  atomicAdd(&gsq[g*F + c], q);
}

__global__ void k_coef(const float* __restrict__ gsum, const float* __restrict__ gsq, const int* __restrict__ gptr,
                       const float* __restrict__ w, const float* __restrict__ b, const float* __restrict__ ms,
                       float* __restrict__ cA, float* __restrict__ cB, int F){
  int i = blockIdx.x*256 + threadIdx.x;
  if (i >= NG*F) return;
  int g = i / F, c = i - g*F;
  float cntf = (float)(gptr[g+1] - gptr[g]);
  float m = gsum[i] / cntf;
  float s = ms[c];
  float ex2 = gsq[i] / cntf;
  float var = ex2 - 2.f*s*m*m + s*s*m*m;
  float inv = rsqrtf(var + 1e-5f);
  float wa = w[c]*inv;
  cA[i] = wa;
  cB[i] = b[c] - wa*m*s;
}

__global__ void k_applyelu(float* __restrict__ x, const int* __restrict__ batch,
                           const float* __restrict__ cA, const float* __restrict__ cB, int F){
  size_t i = (size_t)blockIdx.x*256 + threadIdx.x;
  if (i >= (size_t)NN*F) return;
  int node = (int)(i / F);
  int c = (int)(i - (size_t)node*F);
  int g = batch[node];
  float y = cA[g*F + c]*x[i] + cB[g*F + c];
  x[i] = y > 0.f ? y : expm1f(y);
}

// ---------- orchestration ----------
extern "C" void kernel_launch(void* const* d_in, const int* in_sizes, int n_in,
                              void* d_out, int out_size, void* d_ws, size_t ws_size,
                              hipStream_t stream){
  (void)in_sizes; (void)n_in; (void)out_size; (void)ws_size;
  const float* x     = (const float*)d_in[0];
  const int*   ei    = (const int*)d_in[1];
  const int*   batch = (const int*)d_in[2];
  const float* W[4]  = {(const float*)d_in[3],  (const float*)d_in[7],  (const float*)d_in[11], (const float*)d_in[15]};
  const float* AS[4] = {(const float*)d_in[4],  (const float*)d_in[8],  (const float*)d_in[12], (const float*)d_in[16]};
  const float* AD[4] = {(const float*)d_in[5],  (const float*)d_in[9],  (const float*)d_in[13], (const float*)d_in[17]};
  const float* BI[4] = {(const float*)d_in[6],  (const float*)d_in[10], (const float*)d_in[14], (const float*)d_in[18]};
  const float* GW[3] = {(const float*)d_in[19], (const float*)d_in[22], (const float*)d_in[25]};
  const float* GB[3] = {(const float*)d_in[20], (const float*)d_in[23], (const float*)d_in[26]};
  const float* GA[3] = {(const float*)d_in[21], (const float*)d_in[24], (const float*)d_in[27]};

  float* ws   = (float*)d_ws;
  float* bufA = ws;                                  // [NN,1024]
  float* bufB = bufA + (size_t)NN*1024;              // [NN,1024]
  float* a_s  = bufB + (size_t)NN*1024;              // [NN,4]
  float* a_d  = a_s + (size_t)NN*4;                  // [NN,4]
  float* gsum = a_d + (size_t)NN*4;                  // [NG,1024]
  float* gsq  = gsum + (size_t)NG*1024;              // [NG,1024]
  float* cA   = gsq  + (size_t)NG*1024;              // [NG,1024]
  float* cB   = cA   + (size_t)NG*1024;              // [NG,1024]
  int* ptr  = (int*)(cB + (size_t)NG*1024);          // [NN+1]
  int* fill = ptr + (NN + 8);                        // [NN+1]
  int* csrc = fill + (NN + 8);                       // [E2]
  int* gptr = csrc + E2;                             // [NG+1]

  // ---- CSR + graph boundaries (once per call) ----
  hipMemsetAsync(fill, 0, sizeof(int)*(NN+1), stream);
  k_gptr<<<1, 32, 0, stream>>>(batch, gptr);
  k_count<<<(E2+255)/256, 256, 0, stream>>>(ei, fill);
  k_scan<<<1, 256, 0, stream>>>(fill, ptr);
  k_copy<<<(NN+255)/256, 256, 0, stream>>>(ptr, fill);
  k_scatter<<<(E2+255)/256, 256, 0, stream>>>(ei, fill, csrc);

  const float* cur = x;
  int Kin = 50;
  for (int li = 0; li < 4; ++li){
    int H = (li == 3) ? 1 : 4;
    int C = (li == 3) ? 121 : 256;
    int F = H*C;
    // GEMM: h = cur @ W  -> bufA
    dim3 ggrid((NN + BM - 1)/BM, (F + BN - 1)/BN);
    k_gemm<<<ggrid, 256, 0, stream>>>(cur, W[li], bufA, NN, Kin, F);
    // attention halves
    k_attprep<<<dim3(NN, H), 64, 0, stream>>>(bufA, AS[li], AD[li], a_s, a_d, H, C);
    // softmax + aggregate
    float* gout = (li == 3) ? (float*)d_out : bufB;
    k_gather<<<NN, 256, 0, stream>>>(bufA, a_s, a_d, ptr, csrc, BI[li], gout, H, C);
    if (li < 3){
      // GraphNorm + ELU in-place on bufB
      hipMemsetAsync(gsum, 0, sizeof(float)*2*NG*1024, stream);
      k_gnstats<<<dim3(NG, (F+255)/256, NSPLIT), 256, 0, stream>>>(bufB, gptr, gsum, gsq, F);
      k_coef<<<(NG*F + 255)/256, 256, 0, stream>>>(gsum, gsq, gptr, GW[li], GB[li], GA[li], cA, cB, F);
      size_t tot = (size_t)NN*F;
      k_applyelu<<<(unsigned)((tot + 255)/256), 256, 0, stream>>>(bufB, batch, cA, cB, F);
      cur = bufB;
      Kin = F;
    }
  }
}

// Round 2
// 944.515 us; speedup vs baseline: 1.9425x; 1.9425x over previous
//
#include <hip/hip_runtime.h>
#include <math.h>

#define NN 10000
#define NE 160000
#define E2 (NE + NN)
#define NG 20
#define MPAD 10112   // 79 * 128

typedef __attribute__((ext_vector_type(8))) short short8;
typedef __attribute__((ext_vector_type(4))) float f32x4;

// ---------- helpers ----------
__device__ inline unsigned fenc(float f){ unsigned u=__float_as_uint(f); return (u&0x80000000u)?~u:(u|0x80000000u); }
__device__ inline float fdec(unsigned u){ return __uint_as_float((u&0x80000000u)?(u&0x7FFFFFFFu):~u); }
__device__ inline unsigned short f2bf(float f){
  unsigned u = __float_as_uint(f);
  unsigned r = u + 0x7FFFu + ((u >> 16) & 1u);
  return (unsigned short)(r >> 16);
}
__device__ inline float bf2f(unsigned short h){ return __uint_as_float(((unsigned)h) << 16); }

__device__ inline void gload_lds16(const void* g, void* l){
  __builtin_amdgcn_global_load_lds((const __attribute__((address_space(1))) void*)g,
                                   (__attribute__((address_space(3))) void*)l, 16, 0, 0);
}

// ---------- graph boundary (batch is sorted) ----------
__global__ void k_gptr(const int* __restrict__ batch, int* __restrict__ gptr){
  int g = threadIdx.x;
  if (g > NG) return;
  int lo = 0, hi = NN;
  while (lo < hi){ int mid = (lo+hi)>>1; if (batch[mid] < g) lo = mid+1; else hi = mid; }
  gptr[g] = lo;
}

// ---------- CSR build (by dst, self-loops appended) ----------
__global__ void k_count(const int* __restrict__ ei, int* __restrict__ cnt){
  int e = blockIdx.x*256 + threadIdx.x;
  if (e >= E2) return;
  int d = (e < NE) ? ei[NE + e] : (e - NE);
  atomicAdd(&cnt[d], 1);
}

__global__ void k_scan(const int* __restrict__ cnt, int* __restrict__ ptr){
  __shared__ int tpre[256];
  __shared__ int tsum[256];
  int tid = threadIdx.x;
  const int per = (NN + 255)/256;
  int base = tid*per;
  int s = 0;
  for (int i=0;i<per;i++){ int idx=base+i; if (idx<NN) s += cnt[idx]; }
  tsum[tid] = s;
  __syncthreads();
  if (tid == 0){
    int run = 0;
    for (int i=0;i<256;i++){ tpre[i]=run; run += tsum[i]; }
    ptr[NN] = run;
  }
  __syncthreads();
  int run = tpre[tid];
  for (int i=0;i<per;i++){ int idx=base+i; if (idx<NN){ ptr[idx]=run; run += cnt[idx]; } }
}

__global__ void k_copy(const int* __restrict__ src, int* __restrict__ dst){
  int i = blockIdx.x*256 + threadIdx.x;
  if (i < NN) dst[i] = src[i];
}

__global__ void k_scatter(const int* __restrict__ ei, int* __restrict__ fill, int* __restrict__ csrc){
  int e = blockIdx.x*256 + threadIdx.x;
  if (e >= E2) return;
  int s, d;
  if (e < NE){ s = ei[e]; d = ei[NE + e]; } else { s = d = e - NE; }
  int pos = atomicAdd(&fill[d], 1);
  csrc[pos] = s;
}

// ---------- conversions ----------
__global__ void k_xconv(const float* __restrict__ x, unsigned short* __restrict__ xbf){
  int i = blockIdx.x*256 + threadIdx.x;
  if (i >= MPAD*64) return;
  int r = i >> 6, c = i & 63;
  float v = (r < NN && c < 50) ? x[r*50 + c] : 0.f;
  xbf[i] = f2bf(v);
}

// W: [K][N] row-major f32 -> Wt: [Npad][Kpad] bf16 (transposed, zero-padded)
__global__ void k_wconv(const float* __restrict__ W, unsigned short* __restrict__ Wt,
                        int K, int N, int Kpad, int Npad){
  int i = blockIdx.x*256 + threadIdx.x;
  if (i >= Npad*Kpad) return;
  int nn = i / Kpad, kk = i - nn*Kpad;
  float v = (nn < N && kk < K) ? W[(size_t)kk*N + nn] : 0.f;
  Wt[i] = f2bf(v);
}

// ---------- bf16 MFMA GEMM: C[M,F] = A[Mpad,K] x Bt[Npad,K]^T ----------
// 128x128 tile, BK=32, 4 waves, 4x4 16x16x32 frags per wave (m93/m97 structure)
__global__ __launch_bounds__(256) void k_mfma_gemm(
    const unsigned short* __restrict__ A,   // [>=row0+128][K] bf16
    const unsigned short* __restrict__ Bt,  // [>=col0+128][K] bf16
    unsigned short* __restrict__ Cbf,       // [M][F] bf16 out
    int M, int K, int F)
{
  __shared__ unsigned short sA[128*32];
  __shared__ unsigned short sB[128*32];
  const int tid = threadIdx.x;
  const int wave = tid >> 6;
  const int lane = tid & 63;
  const int row0 = blockIdx.x * 128;
  const int col0 = blockIdx.y * 128;
  const int wr = (wave >> 1) * 64;
  const int wc = (wave & 1) * 64;
  f32x4 acc[4][4];
  #pragma unroll
  for (int i=0;i<4;i++)
    #pragma unroll
    for (int j=0;j<4;j++){ acc[i][j][0]=0.f; acc[i][j][1]=0.f; acc[i][j][2]=0.f; acc[i][j][3]=0.f; }

  const unsigned short* aSrc = A + (size_t)(row0 + (tid>>2))*K + (tid&3)*8;
  const unsigned short* bSrc = Bt + (size_t)(col0 + (tid>>2))*K + (tid&3)*8;
  char* ldsA = (char*)sA + wave*1024;
  char* ldsB = (char*)sB + wave*1024;
  const int koff = (lane >> 4) * 8;

  for (int k0 = 0; k0 < K; k0 += 32){
    gload_lds16(aSrc + k0,                  ldsA);
    gload_lds16(aSrc + (size_t)64*K + k0,   ldsA + 4096);
    gload_lds16(bSrc + k0,                  ldsB);
    gload_lds16(bSrc + (size_t)64*K + k0,   ldsB + 4096);
    __syncthreads();
    short8 af[4], bfr[4];
    #pragma unroll
    for (int m=0;m<4;m++)
      af[m] = *(const short8*)(sA + (wr + m*16 + (lane&15))*32 + koff);
    #pragma unroll
    for (int n=0;n<4;n++)
      bfr[n] = *(const short8*)(sB + (wc + n*16 + (lane&15))*32 + koff);
    #pragma unroll
    for (int m=0;m<4;m++)
      #pragma unroll
      for (int n=0;n<4;n++)
        acc[m][n] = __builtin_amdgcn_mfma_f32_16x16x32_bf16(af[m], bfr[n], acc[m][n], 0, 0, 0);
    __syncthreads();
  }
  const int cr = (lane >> 4) * 4;
  const int cc = lane & 15;
  #pragma unroll
  for (int m=0;m<4;m++){
    #pragma unroll
    for (int n=0;n<4;n++){
      int col = col0 + wc + n*16 + cc;
      if (col >= F) continue;
      #pragma unroll
      for (int r=0;r<4;r++){
        int row = row0 + wr + m*16 + cr + r;
        if (row < M) Cbf[(size_t)row*F + col] = f2bf(acc[m][n][r]);
      }
    }
  }
}

// ---------- per-node per-head attention halves (bf16 h) ----------
__global__ void k_attprep(const unsigned short* __restrict__ h, const float* __restrict__ atts,
                          const float* __restrict__ attd,
                          float* __restrict__ a_s, float* __restrict__ a_d, int H, int C){
  int node = blockIdx.x, head = blockIdx.y;
  int lane = threadIdx.x;           // 64
  int F = H*C;
  const unsigned short* hp = h + (size_t)node*F + head*C;
  const float* sp = atts + head*C;
  const float* dp = attd + head*C;
  float ss = 0.f, sd = 0.f;
  for (int c = lane; c < C; c += 64){ float v = bf2f(hp[c]); ss += v*sp[c]; sd += v*dp[c]; }
  #pragma unroll
  for (int o = 32; o; o >>= 1){ ss += __shfl_down(ss, o); sd += __shfl_down(sd, o); }
  if (lane == 0){ a_s[node*H + head] = ss; a_d[node*H + head] = sd; }
}

// ---------- fused edge-softmax + weighted gather (one block per dst node) ----------
#define CHUNK 128
__global__ __launch_bounds__(256) void k_gather(const unsigned short* __restrict__ h,
                         const float* __restrict__ a_s, const float* __restrict__ a_d,
                         const int* __restrict__ ptr, const int* __restrict__ csrc,
                         const float* __restrict__ bias, float* __restrict__ out, int H, int C){
  int node = blockIdx.x;
  int F = H*C;
  int beg = ptr[node], deg = ptr[node+1] - beg;
  __shared__ unsigned smaxu[4];
  __shared__ float smax[4], ssum[4];
  __shared__ int ssrc[CHUNK];
  __shared__ float salpha[CHUNK*4];
  int tid = threadIdx.x;
  if (tid < H){ smaxu[tid] = fenc(-INFINITY); ssum[tid] = 0.f; }
  __syncthreads();
  for (int i = tid; i < deg*H; i += 256){
    int e = i / H, hh = i - e*H;
    int s = csrc[beg + e];
    float ev = a_s[s*H + hh] + a_d[node*H + hh];
    ev = ev > 0.f ? ev : 0.2f*ev;
    atomicMax(&smaxu[hh], fenc(ev));
  }
  __syncthreads();
  if (tid < H) smax[tid] = fdec(smaxu[tid]);
  __syncthreads();
  for (int i = tid; i < deg*H; i += 256){
    int e = i / H, hh = i - e*H;
    int s = csrc[beg + e];
    float ev = a_s[s*H + hh] + a_d[node*H + hh];
    ev = ev > 0.f ? ev : 0.2f*ev;
    atomicAdd(&ssum[hh], __expf(ev - smax[hh]));
  }
  __syncthreads();
  float acc[4] = {0.f, 0.f, 0.f, 0.f};
  int hd[4];
  int nci = (F + 255) / 256;
  for (int ci = 0; ci < nci; ci++){ int c = tid + ci*256; hd[ci] = (c < F) ? c / C : 0; }
  for (int c0 = 0; c0 < deg; c0 += CHUNK){
    int cn = min(CHUNK, deg - c0);
    for (int i = tid; i < cn*H; i += 256){
      int e = i / H, hh = i - e*H;
      int s = csrc[beg + c0 + e];
      if (hh == 0) ssrc[e] = s;
      float ev = a_s[s*H + hh] + a_d[node*H + hh];
      ev = ev > 0.f ? ev : 0.2f*ev;
      salpha[e*H + hh] = __expf(ev - smax[hh]) / (ssum[hh] + 1e-16f);
    }
    __syncthreads();
    for (int e = 0; e < cn; e++){
      const unsigned short* hp = h + (size_t)ssrc[e]*F;
      float al0 = salpha[e*H + hd[0]];
      for (int ci = 0; ci < nci; ci++){
        int c = tid + ci*256;
        if (c < F) acc[ci] += bf2f(hp[c]) * ((ci == 0) ? al0 : salpha[e*H + hd[ci]]);
      }
    }
    __syncthreads();
  }
  for (int ci = 0; ci < nci; ci++){
    int c = tid + ci*256;
    if (c < F) out[(size_t)node*F + c] = acc[ci] + bias[c];
  }
}

// ---------- GraphNorm stats / coefs / apply+ELU ----------
#define NSPLIT 16
__global__ void k_gnstats(const float* __restrict__ x, const int* __restrict__ gptr,
                          float* __restrict__ gsum, float* __restrict__ gsq, int F){
  int g = blockIdx.x, cc = blockIdx.y, sp = blockIdx.z;
  int c = cc*256 + threadIdx.x;
  if (c >= F) return;
  int beg = gptr[g], end = gptr[g+1];
  int n = end - beg;
  int per = (n + NSPLIT - 1) / NSPLIT;
  int nb = beg + sp*per, ne = min(end, nb + per);
  if (ne <= nb) return;
  float s = 0.f, q = 0.f;
  for (int i = nb; i < ne; i++){ float v = x[(size_t)i*F + c]; s += v; q += v*v; }
  atomicAdd(&gsum[g*F + c], s);
  atomicAdd(&gsq[g*F + c], q);
}

__global__ void k_coef(const float* __restrict__ gsum, const float* __restrict__ gsq, const int* __restrict__ gptr,
                       const float* __restrict__ w, const float* __restrict__ b, const float* __restrict__ ms,
                       float* __restrict__ cA, float* __restrict__ cB, int F){
  int i = blockIdx.x*256 + threadIdx.x;
  if (i >= NG*F) return;
  int g = i / F, c = i - g*F;
  float cntf = (float)(gptr[g+1] - gptr[g]);
  float m = gsum[i] / cntf;
  float s = ms[c];
  float ex2 = gsq[i] / cntf;
  float var = ex2 - 2.f*s*m*m + s*s*m*m;
  float inv = rsqrtf(var + 1e-5f);
  float wa = w[c]*inv;
  cA[i] = wa;
  cB[i] = b[c] - wa*m*s;
}

// read f32, apply affine+ELU, write bf16 (next layer's GEMM input)
__global__ void k_applyelu(const float* __restrict__ x, const int* __restrict__ batch,
                           const float* __restrict__ cA, const float* __restrict__ cB,
                           unsigned short* __restrict__ obf, int F){
  size_t i = (size_t)blockIdx.x*256 + threadIdx.x;
  if (i >= (size_t)NN*F) return;
  int node = (int)(i / F);
  int c = (int)(i - (size_t)node*F);
  int g = batch[node];
  float y = cA[g*F + c]*x[i] + cB[g*F + c];
  y = y > 0.f ? y : expm1f(y);
  obf[i] = f2bf(y);
}

// ---------- orchestration ----------
extern "C" void kernel_launch(void* const* d_in, const int* in_sizes, int n_in,
                              void* d_out, int out_size, void* d_ws, size_t ws_size,
                              hipStream_t stream){
  (void)in_sizes; (void)n_in; (void)out_size; (void)ws_size;
  const float* x     = (const float*)d_in[0];
  const int*   ei    = (const int*)d_in[1];
  const int*   batch = (const int*)d_in[2];
  const float* W[4]  = {(const float*)d_in[3],  (const float*)d_in[7],  (const float*)d_in[11], (const float*)d_in[15]};
  const float* AS[4] = {(const float*)d_in[4],  (const float*)d_in[8],  (const float*)d_in[12], (const float*)d_in[16]};
  const float* AD[4] = {(const float*)d_in[5],  (const float*)d_in[9],  (const float*)d_in[13], (const float*)d_in[17]};
  const float* BI[4] = {(const float*)d_in[6],  (const float*)d_in[10], (const float*)d_in[14], (const float*)d_in[18]};
  const float* GW[3] = {(const float*)d_in[19], (const float*)d_in[22], (const float*)d_in[25]};
  const float* GB[3] = {(const float*)d_in[20], (const float*)d_in[23], (const float*)d_in[26]};
  const float* GA[3] = {(const float*)d_in[21], (const float*)d_in[24], (const float*)d_in[27]};

  float* ws   = (float*)d_ws;
  float* bufB = ws;                                  // [NN,1024] f32 (gather out / gnorm)
  float* a_s  = bufB + (size_t)NN*1024;              // [NN,4]
  float* a_d  = a_s + (size_t)NN*4;                  // [NN,4]
  float* gsum = a_d + (size_t)NN*4;                  // [NG,1024]
  float* gsq  = gsum + (size_t)NG*1024;              // [NG,1024]
  float* cA   = gsq  + (size_t)NG*1024;              // [NG,1024]
  float* cB   = cA   + (size_t)NG*1024;              // [NG,1024]
  int* ptr  = (int*)(cB + (size_t)NG*1024);          // [NN+1]
  int* fill = ptr + (NN + 8);                        // [NN+1]
  int* csrc = fill + (NN + 8);                       // [E2]
  int* gptr = csrc + E2;                             // [NG+1] (pad to 24)
  unsigned short* xbf = (unsigned short*)(gptr + 24);// [MPAD,64] bf16
  unsigned short* abf = xbf + (size_t)MPAD*64;       // [MPAD,1024] bf16 (layer inputs 1-3)
  unsigned short* hbf = abf + (size_t)MPAD*1024;     // [NN,1024] bf16 (GEMM out)
  unsigned short* Wt  = hbf + (size_t)NN*1024;       // [1024,1024] bf16 (per-layer W^T)

  // ---- CSR + graph boundaries (once per call) ----
  hipMemsetAsync(fill, 0, sizeof(int)*(NN+1), stream);
  k_gptr<<<1, 32, 0, stream>>>(batch, gptr);
  k_count<<<(E2+255)/256, 256, 0, stream>>>(ei, fill);
  k_scan<<<1, 256, 0, stream>>>(fill, ptr);
  k_copy<<<(NN+255)/256, 256, 0, stream>>>(ptr, fill);
  k_scatter<<<(E2+255)/256, 256, 0, stream>>>(ei, fill, csrc);
  k_xconv<<<(MPAD*64+255)/256, 256, 0, stream>>>(x, xbf);

  const int Kp[4] = {64, 1024, 1024, 1024};
  const int Kr[4] = {50, 1024, 1024, 1024};
  const int Np[4] = {1024, 1024, 1024, 128};
  for (int li = 0; li < 4; ++li){
    int H = (li == 3) ? 1 : 4;
    int C = (li == 3) ? 121 : 256;
    int F = H*C;
    const unsigned short* Ain = (li == 0) ? xbf : abf;
    // W -> transposed bf16
    k_wconv<<<(Np[li]*Kp[li]+255)/256, 256, 0, stream>>>(W[li], Wt, Kr[li], F, Kp[li], Np[li]);
    // h = Ain @ Wt^T -> hbf (bf16)
    dim3 ggrid(MPAD/128, Np[li]/128);
    k_mfma_gemm<<<ggrid, 256, 0, stream>>>(Ain, Wt, hbf, NN, Kp[li], F);
    // attention halves
    k_attprep<<<dim3(NN, H), 64, 0, stream>>>(hbf, AS[li], AD[li], a_s, a_d, H, C);
    // softmax + aggregate
    float* gout = (li == 3) ? (float*)d_out : bufB;
    k_gather<<<NN, 256, 0, stream>>>(hbf, a_s, a_d, ptr, csrc, BI[li], gout, H, C);
    if (li < 3){
      hipMemsetAsync(gsum, 0, sizeof(float)*2*NG*1024, stream);
      k_gnstats<<<dim3(NG, (F+255)/256, NSPLIT), 256, 0, stream>>>(bufB, gptr, gsum, gsq, F);
      k_coef<<<(NG*F + 255)/256, 256, 0, stream>>>(gsum, gsq, gptr, GW[li], GB[li], GA[li], cA, cB, F);
      size_t tot = (size_t)NN*F;
      k_applyelu<<<(unsigned)((tot + 255)/256), 256, 0, stream>>>(bufB, batch, cA, cB, abf, F);
    }
  }
}

// Round 3
// 592.087 us; speedup vs baseline: 3.0987x; 1.5952x over previous
//
#include <hip/hip_runtime.h>
#include <math.h>

#define NN 10000
#define NE 160000
#define E2 (NE + NN)
#define NG 20
#define MPAD 10112   // 79 * 128

typedef __attribute__((ext_vector_type(8))) short short8;
typedef __attribute__((ext_vector_type(4))) float f32x4;

// ---------- helpers ----------
__device__ inline unsigned short f2bf(float f){
  unsigned u = __float_as_uint(f);
  unsigned r = u + 0x7FFFu + ((u >> 16) & 1u);
  return (unsigned short)(r >> 16);
}
__device__ inline float bf2f(unsigned short h){ return __uint_as_float(((unsigned)h) << 16); }

__device__ inline void gload_lds16(const void* g, void* l){
  __builtin_amdgcn_global_load_lds((const __attribute__((address_space(1))) void*)g,
                                   (__attribute__((address_space(3))) void*)l, 16, 0, 0);
}

// ---------- graph boundary (batch is sorted) ----------
__global__ void k_gptr(const int* __restrict__ batch, int* __restrict__ gptr){
  int g = threadIdx.x;
  if (g > NG) return;
  int lo = 0, hi = NN;
  while (lo < hi){ int mid = (lo+hi)>>1; if (batch[mid] < g) lo = mid+1; else hi = mid; }
  gptr[g] = lo;
}

// ---------- CSR build (by dst, self-loops appended) ----------
__global__ void k_count(const int* __restrict__ ei, int* __restrict__ cnt){
  int e = blockIdx.x*256 + threadIdx.x;
  if (e >= E2) return;
  int d = (e < NE) ? ei[NE + e] : (e - NE);
  atomicAdd(&cnt[d], 1);
}

__global__ void k_scan(const int* __restrict__ cnt, int* __restrict__ ptr){
  __shared__ int tpre[256];
  __shared__ int tsum[256];
  int tid = threadIdx.x;
  const int per = (NN + 255)/256;
  int base = tid*per;
  int s = 0;
  for (int i=0;i<per;i++){ int idx=base+i; if (idx<NN) s += cnt[idx]; }
  tsum[tid] = s;
  __syncthreads();
  if (tid == 0){
    int run = 0;
    for (int i=0;i<256;i++){ tpre[i]=run; run += tsum[i]; }
    ptr[NN] = run;
  }
  __syncthreads();
  int run = tpre[tid];
  for (int i=0;i<per;i++){ int idx=base+i; if (idx<NN){ ptr[idx]=run; run += cnt[idx]; } }
}

__global__ void k_copy(const int* __restrict__ src, int* __restrict__ dst){
  int i = blockIdx.x*256 + threadIdx.x;
  if (i < NN) dst[i] = src[i];
}

__global__ void k_scatter(const int* __restrict__ ei, int* __restrict__ fill, int* __restrict__ csrc){
  int e = blockIdx.x*256 + threadIdx.x;
  if (e >= E2) return;
  int s, d;
  if (e < NE){ s = ei[e]; d = ei[NE + e]; } else { s = d = e - NE; }
  int pos = atomicAdd(&fill[d], 1);
  csrc[pos] = s;
}

// ---------- conversions ----------
__global__ void k_xconv(const float* __restrict__ x, unsigned short* __restrict__ xbf){
  int i = blockIdx.x*256 + threadIdx.x;
  if (i >= MPAD*64) return;
  int r = i >> 6, c = i & 63;
  float v = (r < NN && c < 50) ? x[r*50 + c] : 0.f;
  xbf[i] = f2bf(v);
}

// W: [K][N] row-major f32 -> Wt: [Npad][Kpad] bf16 (transposed, zero-padded)
__global__ void k_wconv(const float* __restrict__ W, unsigned short* __restrict__ Wt,
                        int K, int N, int Kpad, int Npad){
  int i = blockIdx.x*256 + threadIdx.x;
  if (i >= Npad*Kpad) return;
  int nn = i / Kpad, kk = i - nn*Kpad;
  float v = (nn < N && kk < K) ? W[(size_t)kk*N + nn] : 0.f;
  Wt[i] = f2bf(v);
}

// ---------- bf16 MFMA GEMM: C[M,FS] = A[Mpad,K] x Bt[FS,K]^T (FS = padded out stride) ----------
__global__ __launch_bounds__(256) void k_mfma_gemm(
    const unsigned short* __restrict__ A,   // [>=row0+128][K] bf16
    const unsigned short* __restrict__ Bt,  // [>=col0+128][K] bf16
    unsigned short* __restrict__ Cbf,       // [M][FS] bf16 out
    int M, int K, int FS)
{
  __shared__ unsigned short sA[128*32];
  __shared__ unsigned short sB[128*32];
  const int tid = threadIdx.x;
  const int wave = tid >> 6;
  const int lane = tid & 63;
  const int row0 = blockIdx.x * 128;
  const int col0 = blockIdx.y * 128;
  const int wr = (wave >> 1) * 64;
  const int wc = (wave & 1) * 64;
  f32x4 acc[4][4];
  #pragma unroll
  for (int i=0;i<4;i++)
    #pragma unroll
    for (int j=0;j<4;j++){ acc[i][j][0]=0.f; acc[i][j][1]=0.f; acc[i][j][2]=0.f; acc[i][j][3]=0.f; }

  const unsigned short* aSrc = A + (size_t)(row0 + (tid>>2))*K + (tid&3)*8;
  const unsigned short* bSrc = Bt + (size_t)(col0 + (tid>>2))*K + (tid&3)*8;
  char* ldsA = (char*)sA + wave*1024;
  char* ldsB = (char*)sB + wave*1024;
  const int koff = (lane >> 4) * 8;

  for (int k0 = 0; k0 < K; k0 += 32){
    gload_lds16(aSrc + k0,                  ldsA);
    gload_lds16(aSrc + (size_t)64*K + k0,   ldsA + 4096);
    gload_lds16(bSrc + k0,                  ldsB);
    gload_lds16(bSrc + (size_t)64*K + k0,   ldsB + 4096);
    __syncthreads();
    short8 af[4], bfr[4];
    #pragma unroll
    for (int m=0;m<4;m++)
      af[m] = *(const short8*)(sA + (wr + m*16 + (lane&15))*32 + koff);
    #pragma unroll
    for (int n=0;n<4;n++)
      bfr[n] = *(const short8*)(sB + (wc + n*16 + (lane&15))*32 + koff);
    #pragma unroll
    for (int m=0;m<4;m++)
      #pragma unroll
      for (int n=0;n<4;n++)
        acc[m][n] = __builtin_amdgcn_mfma_f32_16x16x32_bf16(af[m], bfr[n], acc[m][n], 0, 0, 0);
    __syncthreads();
  }
  const int cr = (lane >> 4) * 4;
  const int cc = lane & 15;
  #pragma unroll
  for (int m=0;m<4;m++){
    #pragma unroll
    for (int n=0;n<4;n++){
      int col = col0 + wc + n*16 + cc;
      #pragma unroll
      for (int r=0;r<4;r++){
        int row = row0 + wr + m*16 + cr + r;
        if (row < M) Cbf[(size_t)row*FS + col] = f2bf(acc[m][n][r]);
      }
    }
  }
}

// ---------- per-node per-head attention halves (bf16 h, stride FS) ----------
__global__ void k_attprep(const unsigned short* __restrict__ h, const float* __restrict__ atts,
                          const float* __restrict__ attd,
                          float* __restrict__ a_s, float* __restrict__ a_d, int H, int C, int FS){
  int node = blockIdx.x, head = blockIdx.y;
  int lane = threadIdx.x;           // 64
  const unsigned short* hp = h + (size_t)node*FS + head*C;
  const float* sp = atts + head*C;
  const float* dp = attd + head*C;
  float ss = 0.f, sd = 0.f;
  for (int c = lane; c < C; c += 64){ float v = bf2f(hp[c]); ss += v*sp[c]; sd += v*dp[c]; }
  #pragma unroll
  for (int o = 32; o; o >>= 1){ ss += __shfl_down(ss, o); sd += __shfl_down(sd, o); }
  if (lane == 0){ a_s[node*H + head] = ss; a_d[node*H + head] = sd; }
}

// ---------- per-node softmax -> alphaT[h][E2] (one wave per node) ----------
__global__ void k_alpha(const float* __restrict__ a_s, const float* __restrict__ a_d,
                        const int* __restrict__ ptr, const int* __restrict__ csrc,
                        float* __restrict__ alphaT, int H, int LH){
  int node = blockIdx.x;
  int lane = threadIdx.x;   // 64
  int beg = ptr[node], deg = ptr[node+1] - beg;
  int items = deg << LH;    // deg*H
  int hh = lane & (H-1);    // constant per lane (64 % H == 0)
  float ad = a_d[node*H + hh];
  // pass 1: per-head max
  float mx = -INFINITY;
  for (int i = lane; i < items; i += 64){
    int e = i >> LH;
    int s = csrc[beg + e];
    float ev = a_s[s*H + hh] + ad;
    ev = ev > 0.f ? ev : 0.2f*ev;
    mx = fmaxf(mx, ev);
  }
  for (int o = H; o < 64; o <<= 1) mx = fmaxf(mx, __shfl_xor(mx, o));
  // pass 2: per-head denom
  float den = 0.f;
  for (int i = lane; i < items; i += 64){
    int e = i >> LH;
    int s = csrc[beg + e];
    float ev = a_s[s*H + hh] + ad;
    ev = ev > 0.f ? ev : 0.2f*ev;
    den += __expf(ev - mx);
  }
  for (int o = H; o < 64; o <<= 1) den += __shfl_xor(den, o);
  float inv = 1.f / (den + 1e-16f);
  // pass 3: write alpha (transposed per head)
  for (int i = lane; i < items; i += 64){
    int e = i >> LH;
    int s = csrc[beg + e];
    float ev = a_s[s*H + hh] + ad;
    ev = ev > 0.f ? ev : 0.2f*ev;
    alphaT[(size_t)hh*E2 + beg + e] = __expf(ev - mx) * inv;
  }
}

// ---------- weighted gather: grid (NN, H); block covers CS = L*8 channels ----------
// L lanes per edge-group, NGRP = 256/L groups process edges in parallel.
template<int L>
__global__ __launch_bounds__(256) void k_gather2(
    const unsigned short* __restrict__ h, int FS,
    const float* __restrict__ alphaT,
    const int* __restrict__ ptr, const int* __restrict__ csrc,
    const float* __restrict__ bias, float* __restrict__ out,
    int F, int C, int outF)
{
  constexpr int NGRP = 256 / L;
  constexpr int CS = L * 8;
  const int node = blockIdx.x;
  const int head = blockIdx.y;
  const int colbase = head * C;
  const int beg = ptr[node], deg = ptr[node+1] - beg;
  __shared__ int ssrc[256];
  __shared__ float sal[256];
  __shared__ float red[NGRP * CS];   // 8 KB
  const int tid = threadIdx.x;
  const int grp = tid / L, li = tid % L;
  const int c0 = colbase + li*8;
  const float* aT = alphaT + (size_t)head*E2 + beg;
  float acc[8] = {0.f,0.f,0.f,0.f,0.f,0.f,0.f,0.f};
  for (int b0 = 0; b0 < deg; b0 += 256){
    int bn = min(256, deg - b0);
    if (tid < bn){ ssrc[tid] = csrc[beg + b0 + tid]; sal[tid] = aT[b0 + tid]; }
    __syncthreads();
    for (int e = grp; e < bn; e += NGRP){
      int s = ssrc[e];
      float al = sal[e];
      short8 v = *(const short8*)(h + (size_t)s*FS + c0);
      #pragma unroll
      for (int j=0;j<8;j++) acc[j] += bf2f((unsigned short)v[j]) * al;
    }
    __syncthreads();
  }
  #pragma unroll
  for (int j=0;j<8;j++) red[grp*CS + li*8 + j] = acc[j];
  __syncthreads();
  for (int c = tid; c < CS; c += 256){
    float s = 0.f;
    #pragma unroll
    for (int g=0; g<NGRP; g++) s += red[g*CS + c];
    int oc = colbase + c;
    if (oc < F) out[(size_t)node*outF + oc] = s + bias[oc];
  }
}

// ---------- GraphNorm stats / coefs / apply+ELU ----------
#define NSPLIT 16
__global__ void k_gnstats(const float* __restrict__ x, const int* __restrict__ gptr,
                          float* __restrict__ gsum, float* __restrict__ gsq, int F){
  int g = blockIdx.x, cc = blockIdx.y, sp = blockIdx.z;
  int c = cc*256 + threadIdx.x;
  if (c >= F) return;
  int beg = gptr[g], end = gptr[g+1];
  int n = end - beg;
  int per = (n + NSPLIT - 1) / NSPLIT;
  int nb = beg + sp*per, ne = min(end, nb + per);
  if (ne <= nb) return;
  float s = 0.f, q = 0.f;
  for (int i = nb; i < ne; i++){ float v = x[(size_t)i*F + c]; s += v; q += v*v; }
  atomicAdd(&gsum[g*F + c], s);
  atomicAdd(&gsq[g*F + c], q);
}

__global__ void k_coef(const float* __restrict__ gsum, const float* __restrict__ gsq, const int* __restrict__ gptr,
                       const float* __restrict__ w, const float* __restrict__ b, const float* __restrict__ ms,
                       float* __restrict__ cA, float* __restrict__ cB, int F){
  int i = blockIdx.x*256 + threadIdx.x;
  if (i >= NG*F) return;
  int g = i / F, c = i - g*F;
  float cntf = (float)(gptr[g+1] - gptr[g]);
  float m = gsum[i] / cntf;
  float s = ms[c];
  float ex2 = gsq[i] / cntf;
  float var = ex2 - 2.f*s*m*m + s*s*m*m;
  float inv = rsqrtf(var + 1e-5f);
  float wa = w[c]*inv;
  cA[i] = wa;
  cB[i] = b[c] - wa*m*s;
}

__global__ void k_applyelu(const float* __restrict__ x, const int* __restrict__ batch,
                           const float* __restrict__ cA, const float* __restrict__ cB,
                           unsigned short* __restrict__ obf, int F){
  size_t i = (size_t)blockIdx.x*256 + threadIdx.x;
  if (i >= (size_t)NN*F) return;
  int node = (int)(i / F);
  int c = (int)(i - (size_t)node*F);
  int g = batch[node];
  float y = cA[g*F + c]*x[i] + cB[g*F + c];
  y = y > 0.f ? y : expm1f(y);
  obf[i] = f2bf(y);
}

// ---------- orchestration ----------
extern "C" void kernel_launch(void* const* d_in, const int* in_sizes, int n_in,
                              void* d_out, int out_size, void* d_ws, size_t ws_size,
                              hipStream_t stream){
  (void)in_sizes; (void)n_in; (void)out_size; (void)ws_size;
  const float* x     = (const float*)d_in[0];
  const int*   ei    = (const int*)d_in[1];
  const int*   batch = (const int*)d_in[2];
  const float* W[4]  = {(const float*)d_in[3],  (const float*)d_in[7],  (const float*)d_in[11], (const float*)d_in[15]};
  const float* AS[4] = {(const float*)d_in[4],  (const float*)d_in[8],  (const float*)d_in[12], (const float*)d_in[16]};
  const float* AD[4] = {(const float*)d_in[5],  (const float*)d_in[9],  (const float*)d_in[13], (const float*)d_in[17]};
  const float* BI[4] = {(const float*)d_in[6],  (const float*)d_in[10], (const float*)d_in[14], (const float*)d_in[18]};
  const float* GW[3] = {(const float*)d_in[19], (const float*)d_in[22], (const float*)d_in[25]};
  const float* GB[3] = {(const float*)d_in[20], (const float*)d_in[23], (const float*)d_in[26]};
  const float* GA[3] = {(const float*)d_in[21], (const float*)d_in[24], (const float*)d_in[27]};

  float* ws   = (float*)d_ws;
  float* bufB = ws;                                  // [NN,1024] f32 (gather out / gnorm)
  float* a_s  = bufB + (size_t)NN*1024;              // [NN,4]
  float* a_d  = a_s + (size_t)NN*4;                  // [NN,4]
  float* gsum = a_d + (size_t)NN*4;                  // [NG,1024]
  float* gsq  = gsum + (size_t)NG*1024;              // [NG,1024]
  float* cA   = gsq  + (size_t)NG*1024;              // [NG,1024]
  float* cB   = cA   + (size_t)NG*1024;              // [NG,1024]
  float* alphaT = cB + (size_t)NG*1024;              // [4][E2]
  int* ptr  = (int*)(alphaT + (size_t)4*E2);         // [NN+1]
  int* fill = ptr + (NN + 8);                        // [NN+1]
  int* csrc = fill + (NN + 8);                       // [E2]
  int* gptr = csrc + E2;                             // [NG+1] (pad to 24)
  unsigned short* xbf = (unsigned short*)(gptr + 24);// [MPAD,64] bf16
  unsigned short* abf = xbf + (size_t)MPAD*64;       // [MPAD,1024] bf16 (layer inputs 1-3)
  unsigned short* hbf = abf + (size_t)MPAD*1024;     // [NN,1024] bf16 (GEMM out)
  unsigned short* Wt  = hbf + (size_t)NN*1024;       // [1024,1024] bf16 (per-layer W^T)

  // ---- CSR + graph boundaries (once per call) ----
  hipMemsetAsync(fill, 0, sizeof(int)*(NN+1), stream);
  k_gptr<<<1, 32, 0, stream>>>(batch, gptr);
  k_count<<<(E2+255)/256, 256, 0, stream>>>(ei, fill);
  k_scan<<<1, 256, 0, stream>>>(fill, ptr);
  k_copy<<<(NN+255)/256, 256, 0, stream>>>(ptr, fill);
  k_scatter<<<(E2+255)/256, 256, 0, stream>>>(ei, fill, csrc);
  k_xconv<<<(MPAD*64+255)/256, 256, 0, stream>>>(x, xbf);

  const int Kp[4]  = {64, 1024, 1024, 1024};
  const int Kr[4]  = {50, 1024, 1024, 1024};
  const int Np[4]  = {1024, 1024, 1024, 128};
  for (int li = 0; li < 4; ++li){
    int H = (li == 3) ? 1 : 4;
    int LH = (li == 3) ? 0 : 2;
    int C = (li == 3) ? 121 : 256;
    int F = H*C;
    int FS = Np[li];                       // padded h stride (1024 / 128)
    const unsigned short* Ain = (li == 0) ? xbf : abf;
    k_wconv<<<(Np[li]*Kp[li]+255)/256, 256, 0, stream>>>(W[li], Wt, Kr[li], F, Kp[li], Np[li]);
    dim3 ggrid(MPAD/128, Np[li]/128);
    k_mfma_gemm<<<ggrid, 256, 0, stream>>>(Ain, Wt, hbf, NN, Kp[li], FS);
    k_attprep<<<dim3(NN, H), 64, 0, stream>>>(hbf, AS[li], AD[li], a_s, a_d, H, C, FS);
    k_alpha<<<NN, 64, 0, stream>>>(a_s, a_d, ptr, csrc, alphaT, H, LH);
    float* gout = (li == 3) ? (float*)d_out : bufB;
    if (li < 3)
      k_gather2<32><<<dim3(NN, 4), 256, 0, stream>>>(hbf, FS, alphaT, ptr, csrc, BI[li], gout, F, C, F);
    else
      k_gather2<16><<<dim3(NN, 1), 256, 0, stream>>>(hbf, FS, alphaT, ptr, csrc, BI[li], gout, F, C, F);
    if (li < 3){
      hipMemsetAsync(gsum, 0, sizeof(float)*2*NG*1024, stream);
      k_gnstats<<<dim3(NG, (F+255)/256, NSPLIT), 256, 0, stream>>>(bufB, gptr, gsum, gsq, F);
      k_coef<<<(NG*F + 255)/256, 256, 0, stream>>>(gsum, gsq, gptr, GW[li], GB[li], GA[li], cA, cB, F);
      size_t tot = (size_t)NN*F;
      k_applyelu<<<(unsigned)((tot + 255)/256), 256, 0, stream>>>(bufB, batch, cA, cB, abf, F);
    }
  }
}